// Round 4
// baseline (6405.178 us; speedup 1.0000x reference)
//
#include <hip/hip_runtime.h>
#include <stdint.h>

#define U_N 100000
#define I_N 50000
#define D_DIM 64
#define E_N 6400000
#define B_N 16384
#define N_N 150000
#define LAYERS 3
#define NB 1024          // buckets
#define BKN 147          // nodes per bucket: ceil(150000/1024)

typedef unsigned long long ull;

// ---------- bucket histogram, LDS-privatized ----------
__global__ __launch_bounds__(256) void bhist(const int* __restrict__ dst,
                                             int* __restrict__ btot) {
    __shared__ int h[NB];
    for (int i = threadIdx.x; i < NB; i += 256) h[i] = 0;
    __syncthreads();
    int chunk = (E_N + gridDim.x - 1) / gridDim.x;
    int beg = blockIdx.x * chunk;
    int end = min(E_N, beg + chunk);
    for (int e = beg + (int)threadIdx.x; e < end; e += 256)
        atomicAdd(&h[(unsigned)dst[e] / BKN], 1);
    __syncthreads();
    for (int i = threadIdx.x; i < NB; i += 256)
        if (h[i]) atomicAdd(&btot[i], h[i]);
}

// ---------- exclusive scan of 1024 bucket totals (one block) ----------
__global__ __launch_bounds__(NB) void scan_buckets(const int* __restrict__ btot,
                                                   int* __restrict__ bbase,
                                                   int* __restrict__ bcur) {
    __shared__ int lds[NB];
    int t = threadIdx.x;
    int x = btot[t];
    lds[t] = x;
    __syncthreads();
    for (int off = 1; off < NB; off <<= 1) {
        int v = (t >= off) ? lds[t - off] : 0;
        __syncthreads();
        lds[t] += v;
        __syncthreads();
    }
    int excl = lds[t] - x;
    bbase[t] = excl;
    bcur[t] = excl;
    if (t == NB - 1) bbase[NB] = lds[NB - 1];   // == E
}

// ---------- phase A: block-privatized bucket partition ----------
// record = val(32) | dst_local(8) @bit18 | src(18)
__global__ __launch_bounds__(256) void phaseA(const int* __restrict__ src,
                                              const int* __restrict__ dst,
                                              const float* __restrict__ vals,
                                              int* __restrict__ bcur,
                                              ull* __restrict__ staging) {
    __shared__ int h[NB];
    __shared__ int base[NB];
    int chunk = (E_N + gridDim.x - 1) / gridDim.x;
    int beg = blockIdx.x * chunk;
    int end = min(E_N, beg + chunk);
    for (int i = threadIdx.x; i < NB; i += 256) h[i] = 0;
    __syncthreads();
    for (int e = beg + (int)threadIdx.x; e < end; e += 256)
        atomicAdd(&h[(unsigned)dst[e] / BKN], 1);
    __syncthreads();
    for (int i = threadIdx.x; i < NB; i += 256) {
        int c = h[i];
        base[i] = c ? atomicAdd(&bcur[i], c) : 0;
    }
    __syncthreads();
    for (int i = threadIdx.x; i < NB; i += 256) h[i] = 0;  // reuse as cursor
    __syncthreads();
    for (int e = beg + (int)threadIdx.x; e < end; e += 256) {
        unsigned d = (unsigned)dst[e];
        unsigned b = d / BKN;
        unsigned local = d - b * BKN;
        int pos = base[b] + atomicAdd(&h[b], 1);
        ull rec = ((ull)__float_as_uint(vals[e]) << 32)
                | ((ull)local << 18)
                | (ull)(unsigned)src[e];
        staging[pos] = rec;
    }
}

// ---------- SpMM: one block per bucket, LDS f32 accumulators ----------
// Records read at wave-uniform (scalar) addresses; 16 gathers in flight/wave.
__global__ __launch_bounds__(256) void spmm_bucket(const float* __restrict__ bu,
                                                   const float* __restrict__ bi,
                                                   float* __restrict__ enext,
                                                   const int* __restrict__ bbase,
                                                   const ull* __restrict__ staging) {
    __shared__ float4 accs4[BKN * (D_DIM / 4)];   // 37632 B
    float* accs = (float*)accs4;
    const int b = blockIdx.x;
    const int node0 = b * BKN;
    if (node0 >= N_N) return;                     // empty trailing buckets
    const int tid = threadIdx.x;
    const int lane = tid & 63;
    const int wu = __builtin_amdgcn_readfirstlane(tid >> 6);

    for (int i = tid; i < BKN * (D_DIM / 4); i += 256)
        accs4[i] = make_float4(0.f, 0.f, 0.f, 0.f);
    __syncthreads();

    const int beg = bbase[b];
    const int end = bbase[b + 1];

    for (int cb = beg + wu * 16; cb + 16 <= end; cb += 64) {
        float g[16];
        float vv[16];
        int   ll[16];
#pragma unroll
        for (int k = 0; k < 16; ++k) {
            ull r = staging[cb + k];              // uniform -> scalar load
            int s = (int)(r & 0x3FFFFu);
            ll[k] = (int)((r >> 18) & 0xFFu);
            vv[k] = __uint_as_float((unsigned)(r >> 32));
            const float* srcp = (s < U_N) ? (bu + (size_t)s * D_DIM)
                                          : (bi + (size_t)(s - U_N) * D_DIM);
            g[k] = srcp[lane];                    // 256B coalesced gather
        }
#pragma unroll
        for (int k = 0; k < 16; ++k)
            atomicAdd(accs + ll[k] * D_DIM + lane, vv[k] * g[k]);
    }
    int rem = (end - beg) & 15;
    if (wu == 0 && rem) {
        for (int e = end - rem; e < end; ++e) {
            ull r = staging[e];
            int s = (int)(r & 0x3FFFFu);
            int l = (int)((r >> 18) & 0xFFu);
            float v = __uint_as_float((unsigned)(r >> 32));
            const float* srcp = (s < U_N) ? (bu + (size_t)s * D_DIM)
                                          : (bi + (size_t)(s - U_N) * D_DIM);
            atomicAdd(accs + l * D_DIM + lane, v * srcp[lane]);
        }
    }
    __syncthreads();
    const int rows = min(BKN, N_N - node0);
    float4* e4 = (float4*)(enext + (size_t)node0 * D_DIM);
    for (int i = tid; i < rows * (D_DIM / 4); i += 256)
        e4[i] = accs4[i];
}

// ---------- accumulate sampled rows into su/si ----------
__global__ __launch_bounds__(256) void accum_batch(const float* __restrict__ bu,
                                                   const float* __restrict__ bi,
                                                   const int* __restrict__ users,
                                                   const int* __restrict__ items,
                                                   float* __restrict__ su,
                                                   float* __restrict__ si) {
    int r = blockIdx.x * 4 + (threadIdx.x >> 6);
    int lane = threadIdx.x & 63;
    if (r >= 2 * B_N) return;
    if (r < B_N) {
        int node = users[r];
        su[(size_t)r * D_DIM + lane] += bu[(size_t)node * D_DIM + lane];
    } else {
        int q = r - B_N;
        int node = items[q];
        si[(size_t)q * D_DIM + lane] += bi[(size_t)node * D_DIM + lane];
    }
}

// ---------- gamma = su.si/16 + 64*(ub+ib) ----------
__global__ __launch_bounds__(256) void gamma_kernel(const float* __restrict__ su,
                                                    const float* __restrict__ si,
                                                    const float* __restrict__ ub,
                                                    const float* __restrict__ ib,
                                                    const int* __restrict__ users,
                                                    const int* __restrict__ items,
                                                    float* __restrict__ out) {
    int b = blockIdx.x * 4 + (threadIdx.x >> 6);
    int lane = threadIdx.x & 63;
    if (b >= B_N) return;
    float p = su[(size_t)b * D_DIM + lane] * si[(size_t)b * D_DIM + lane];
#pragma unroll
    for (int off = 32; off > 0; off >>= 1) p += __shfl_xor(p, off, 64);
    if (lane == 0) {
        float bias = ub[users[b]] + ib[items[b]];
        out[b] = p * (1.0f / 16.0f) + 64.0f * bias;
    }
}

extern "C" void kernel_launch(void* const* d_in, const int* in_sizes, int n_in,
                              void* d_out, int out_size, void* d_ws, size_t ws_size,
                              hipStream_t stream) {
    const float* user_emb  = (const float*)d_in[0];
    const float* item_emb  = (const float*)d_in[1];
    const float* user_bias = (const float*)d_in[2];
    const float* item_bias = (const float*)d_in[3];
    const float* vals      = (const float*)d_in[4];
    const int*   src       = (const int*)d_in[5];
    const int*   dst       = (const int*)d_in[6];
    const int*   users     = (const int*)d_in[7];
    const int*   items     = (const int*)d_in[8];
    float* out = (float*)d_out;

    char* ws = (char*)d_ws;
    size_t off = 0;
    auto alloc = [&](size_t bytes) -> void* {
        void* p = ws + off;
        off += (bytes + 255) & ~(size_t)255;
        return p;
    };
    float* embA    = (float*)alloc(sizeof(float) * (size_t)N_N * D_DIM);   // 38.4MB
    float* embB    = (float*)alloc(sizeof(float) * (size_t)N_N * D_DIM);   // 38.4MB
    float* su      = (float*)alloc(sizeof(float) * (size_t)B_N * D_DIM);   // 4.2MB
    float* si      = (float*)alloc(sizeof(float) * (size_t)B_N * D_DIM);   // 4.2MB
    int*   btot    = (int*)alloc(sizeof(int) * NB);
    int*   bbase   = (int*)alloc(sizeof(int) * (NB + 1));
    int*   bcur    = (int*)alloc(sizeof(int) * NB);
    ull*   staging = (ull*)alloc(sizeof(ull) * (size_t)E_N);               // 51.2MB

    hipMemsetAsync(su, 0, sizeof(float) * (size_t)B_N * D_DIM * 2, stream);
    hipMemsetAsync(btot, 0, sizeof(int) * NB, stream);

    bhist<<<512, 256, 0, stream>>>(dst, btot);
    scan_buckets<<<1, NB, 0, stream>>>(btot, bbase, bcur);
    phaseA<<<512, 256, 0, stream>>>(src, dst, vals, bcur, staging);

    const size_t UD = (size_t)U_N * D_DIM;

    // layer 0 contribution (read inputs in place)
    accum_batch<<<(2 * B_N) / 4, 256, 0, stream>>>(user_emb, item_emb, users,
                                                   items, su, si);
    // layer 1: inputs in place -> embA
    spmm_bucket<<<NB, 256, 0, stream>>>(user_emb, item_emb, embA, bbase, staging);
    accum_batch<<<(2 * B_N) / 4, 256, 0, stream>>>(embA, embA + UD, users,
                                                   items, su, si);
    // layer 2: embA -> embB
    spmm_bucket<<<NB, 256, 0, stream>>>(embA, embA + UD, embB, bbase, staging);
    accum_batch<<<(2 * B_N) / 4, 256, 0, stream>>>(embB, embB + UD, users,
                                                   items, su, si);
    // layer 3: embB -> embA
    spmm_bucket<<<NB, 256, 0, stream>>>(embB, embB + UD, embA, bbase, staging);
    accum_batch<<<(2 * B_N) / 4, 256, 0, stream>>>(embA, embA + UD, users,
                                                   items, su, si);

    gamma_kernel<<<B_N / 4, 256, 0, stream>>>(su, si, user_bias, item_bias,
                                              users, items, out);
}

// Round 5
// 937.832 us; speedup vs baseline: 6.8298x; 6.8298x over previous
//
#include <hip/hip_runtime.h>
#include <stdint.h>

#define U_N 100000
#define I_N 50000
#define D_DIM 64
#define E_N 6400000
#define B_N 16384
#define N_N 150000
#define LAYERS 3
#define NB 1024          // buckets
#define BKN 147          // nodes per bucket: ceil(150000/1024)
#define CAP 8192         // phaseB LDS record capacity (64KB)

typedef unsigned long long ull;

// ---------- init: emb0 = concat(user_emb, item_emb) ----------
__global__ __launch_bounds__(256) void init_emb(const float4* __restrict__ ue,
                                                const float4* __restrict__ ie,
                                                float4* __restrict__ emb) {
    const int n4 = N_N * D_DIM / 4;
    const int u4 = U_N * D_DIM / 4;
    for (int i = blockIdx.x * blockDim.x + threadIdx.x; i < n4;
         i += gridDim.x * blockDim.x) {
        emb[i] = (i < u4) ? ue[i] : ie[i - u4];
    }
}

// ---------- bucket histogram, LDS-privatized ----------
__global__ __launch_bounds__(256) void bhist(const int* __restrict__ dst,
                                             int* __restrict__ btot) {
    __shared__ int h[NB];
    for (int i = threadIdx.x; i < NB; i += 256) h[i] = 0;
    __syncthreads();
    int chunk = (E_N + gridDim.x - 1) / gridDim.x;
    int beg = blockIdx.x * chunk;
    int end = min(E_N, beg + chunk);
    for (int e = beg + (int)threadIdx.x; e < end; e += 256)
        atomicAdd(&h[(unsigned)dst[e] / BKN], 1);
    __syncthreads();
    for (int i = threadIdx.x; i < NB; i += 256)
        if (h[i]) atomicAdd(&btot[i], h[i]);
}

// ---------- exclusive scan of 1024 bucket totals (one block) ----------
__global__ __launch_bounds__(NB) void scan_buckets(const int* __restrict__ btot,
                                                   int* __restrict__ bbase,
                                                   int* __restrict__ bcur,
                                                   int* __restrict__ row_ptr) {
    __shared__ int lds[NB];
    int t = threadIdx.x;
    int x = btot[t];
    lds[t] = x;
    __syncthreads();
    for (int off = 1; off < NB; off <<= 1) {
        int v = (t >= off) ? lds[t - off] : 0;
        __syncthreads();
        lds[t] += v;
        __syncthreads();
    }
    int excl = lds[t] - x;
    bbase[t] = excl;
    bcur[t] = excl;
    if (t == NB - 1) {
        bbase[NB] = lds[NB - 1];
        row_ptr[N_N] = lds[NB - 1];   // == E
    }
}

// ---------- phase A: block-privatized bucket partition ----------
// record = val(32) | dst_local(8) @bit18 | src(18)
__global__ __launch_bounds__(256) void phaseA(const int* __restrict__ src,
                                              const int* __restrict__ dst,
                                              const float* __restrict__ vals,
                                              int* __restrict__ bcur,
                                              ull* __restrict__ staging) {
    __shared__ int h[NB];
    __shared__ int base[NB];
    int chunk = (E_N + gridDim.x - 1) / gridDim.x;
    int beg = blockIdx.x * chunk;
    int end = min(E_N, beg + chunk);
    for (int i = threadIdx.x; i < NB; i += 256) h[i] = 0;
    __syncthreads();
    for (int e = beg + (int)threadIdx.x; e < end; e += 256)
        atomicAdd(&h[(unsigned)dst[e] / BKN], 1);
    __syncthreads();
    for (int i = threadIdx.x; i < NB; i += 256) {
        int c = h[i];
        base[i] = c ? atomicAdd(&bcur[i], c) : 0;
    }
    __syncthreads();
    for (int i = threadIdx.x; i < NB; i += 256) h[i] = 0;  // reuse as cursor
    __syncthreads();
    for (int e = beg + (int)threadIdx.x; e < end; e += 256) {
        unsigned d = (unsigned)dst[e];
        unsigned b = d / BKN;
        unsigned local = d - b * BKN;
        int pos = base[b] + atomicAdd(&h[b], 1);
        ull rec = ((ull)__float_as_uint(vals[e]) << 32)
                | ((ull)local << 18)
                | (ull)(unsigned)src[e];
        staging[pos] = rec;
    }
}

// ---------- phase B: one block per bucket; LDS-stage, sort, emit CSR+row_ptr ----------
__global__ __launch_bounds__(256) void phaseB(const ull* __restrict__ staging,
                                              const int* __restrict__ bbase,
                                              int2* __restrict__ csr,
                                              int* __restrict__ row_ptr) {
    __shared__ ull recs[CAP];
    __shared__ int hist[BKN];
    __shared__ int curs[BKN];
    int b = blockIdx.x;
    int beg = bbase[b];
    int cnt = bbase[b + 1] - beg;
    bool inlds = (cnt <= CAP);
    for (int i = threadIdx.x; i < BKN; i += 256) hist[i] = 0;
    __syncthreads();
    for (int i = threadIdx.x; i < cnt; i += 256) {
        ull rec = staging[beg + i];
        if (inlds) recs[i] = rec;
        atomicAdd(&hist[(int)((rec >> 18) & 0xFF)], 1);
    }
    __syncthreads();
    // wave 0: exclusive scan of 147 counts; write row_ptr + cursors
    if (threadIdx.x < 64) {
        int lane = threadIdx.x;
        int carry = 0;
        for (int c = 0; c < BKN; c += 64) {
            int i = c + lane;
            int x = (i < BKN) ? hist[i] : 0;
            int inc = x;
#pragma unroll
            for (int off = 1; off < 64; off <<= 1) {
                int v = __shfl_up(inc, off, 64);
                if (lane >= off) inc += v;
            }
            int excl = carry + inc - x;
            if (i < BKN) {
                int node = b * BKN + i;
                if (node < N_N) row_ptr[node] = beg + excl;
                curs[i] = excl;
            }
            carry += __shfl(inc, 63, 64);
        }
    }
    __syncthreads();
    for (int i = threadIdx.x; i < cnt; i += 256) {
        ull rec = inlds ? recs[i] : staging[beg + i];
        int local = (int)((rec >> 18) & 0xFF);
        int pos = atomicAdd(&curs[local], 1);
        csr[beg + pos] = make_int2((int)(rec & 0x3FFFFull), (int)(rec >> 32));
    }
}

// ---------- SpMM pull: one wave per row, 16-deep staged gathers ----------
__global__ __launch_bounds__(256) void spmm_kernel(const float* __restrict__ ecur,
                                                   float* __restrict__ enext,
                                                   const int* __restrict__ row_ptr,
                                                   const int2* __restrict__ csr) {
    int row = blockIdx.x * 4 + (threadIdx.x >> 6);
    int lane = threadIdx.x & 63;
    if (row >= N_N) return;
    int beg = row_ptr[row];
    int end = row_ptr[row + 1];
    float acc = 0.0f;
    for (int base = beg; base < end; base += 64) {
        // masked lanes get (0,0): s=0 is a safe gather, v=0 contributes nothing
        int2 rec = (base + lane < end) ? csr[base + lane] : make_int2(0, 0);
        int cnt = min(64, end - base);
        for (int j0 = 0; j0 < cnt; j0 += 16) {
            float g[16], v[16];
#pragma unroll
            for (int k = 0; k < 16; ++k) {
                int s = __shfl(rec.x, j0 + k, 64);
                v[k] = __int_as_float(__shfl(rec.y, j0 + k, 64));
                g[k] = ecur[(size_t)s * D_DIM + lane];   // 16 independent gathers in flight
            }
#pragma unroll
            for (int k = 0; k < 16; ++k)
                acc += v[k] * g[k];
        }
    }
    enext[(size_t)row * D_DIM + lane] = acc;
}

// ---------- accumulate sampled rows into su/si ----------
__global__ __launch_bounds__(256) void accum_batch(const float* __restrict__ emb,
                                                   const int* __restrict__ users,
                                                   const int* __restrict__ items,
                                                   float* __restrict__ su,
                                                   float* __restrict__ si) {
    int r = blockIdx.x * 4 + (threadIdx.x >> 6);
    int lane = threadIdx.x & 63;
    if (r >= 2 * B_N) return;
    if (r < B_N) {
        int node = users[r];
        su[(size_t)r * D_DIM + lane] += emb[(size_t)node * D_DIM + lane];
    } else {
        int b = r - B_N;
        int node = U_N + items[b];
        si[(size_t)b * D_DIM + lane] += emb[(size_t)node * D_DIM + lane];
    }
}

// ---------- gamma = su.si/16 + 64*(ub+ib) ----------
__global__ __launch_bounds__(256) void gamma_kernel(const float* __restrict__ su,
                                                    const float* __restrict__ si,
                                                    const float* __restrict__ ub,
                                                    const float* __restrict__ ib,
                                                    const int* __restrict__ users,
                                                    const int* __restrict__ items,
                                                    float* __restrict__ out) {
    int b = blockIdx.x * 4 + (threadIdx.x >> 6);
    int lane = threadIdx.x & 63;
    if (b >= B_N) return;
    float p = su[(size_t)b * D_DIM + lane] * si[(size_t)b * D_DIM + lane];
#pragma unroll
    for (int off = 32; off > 0; off >>= 1) p += __shfl_xor(p, off, 64);
    if (lane == 0) {
        float bias = ub[users[b]] + ib[items[b]];
        out[b] = p * (1.0f / 16.0f) + 64.0f * bias;
    }
}

extern "C" void kernel_launch(void* const* d_in, const int* in_sizes, int n_in,
                              void* d_out, int out_size, void* d_ws, size_t ws_size,
                              hipStream_t stream) {
    const float* user_emb  = (const float*)d_in[0];
    const float* item_emb  = (const float*)d_in[1];
    const float* user_bias = (const float*)d_in[2];
    const float* item_bias = (const float*)d_in[3];
    const float* vals      = (const float*)d_in[4];
    const int*   src       = (const int*)d_in[5];
    const int*   dst       = (const int*)d_in[6];
    const int*   users     = (const int*)d_in[7];
    const int*   items     = (const int*)d_in[8];
    float* out = (float*)d_out;

    char* ws = (char*)d_ws;
    size_t off = 0;
    auto alloc = [&](size_t bytes) -> void* {
        void* p = ws + off;
        off += (bytes + 255) & ~(size_t)255;
        return p;
    };
    float* emb0    = (float*)alloc(sizeof(float) * (size_t)N_N * D_DIM);   // 38.4MB
    float* emb1    = (float*)alloc(sizeof(float) * (size_t)N_N * D_DIM);   // 38.4MB
    float* su      = (float*)alloc(sizeof(float) * (size_t)B_N * D_DIM);   // 4.2MB
    float* si      = (float*)alloc(sizeof(float) * (size_t)B_N * D_DIM);   // 4.2MB
    int*   row_ptr = (int*)alloc(sizeof(int) * (N_N + 1));                 // 0.6MB
    int*   btot    = (int*)alloc(sizeof(int) * NB);
    int*   bbase   = (int*)alloc(sizeof(int) * (NB + 1));
    int*   bcur    = (int*)alloc(sizeof(int) * NB);
    int2*  csr     = (int2*)alloc(sizeof(int2) * (size_t)E_N);             // 51.2MB
    ull*   staging = (ull*)alloc(sizeof(ull) * (size_t)E_N);               // 51.2MB

    hipMemsetAsync(su, 0, sizeof(float) * (size_t)B_N * D_DIM * 2, stream);
    hipMemsetAsync(btot, 0, sizeof(int) * NB, stream);

    init_emb<<<2048, 256, 0, stream>>>((const float4*)user_emb,
                                       (const float4*)item_emb, (float4*)emb0);
    bhist<<<512, 256, 0, stream>>>(dst, btot);
    scan_buckets<<<1, NB, 0, stream>>>(btot, bbase, bcur, row_ptr);
    phaseA<<<512, 256, 0, stream>>>(src, dst, vals, bcur, staging);
    phaseB<<<NB, 256, 0, stream>>>(staging, bbase, csr, row_ptr);

    // layer 0 contribution
    accum_batch<<<(2 * B_N) / 4, 256, 0, stream>>>(emb0, users, items, su, si);

    float* cur = emb0;
    float* nxt = emb1;
    for (int l = 0; l < LAYERS; ++l) {
        spmm_kernel<<<(N_N + 3) / 4, 256, 0, stream>>>(cur, nxt, row_ptr, csr);
        accum_batch<<<(2 * B_N) / 4, 256, 0, stream>>>(nxt, users, items, su, si);
        float* t = cur; cur = nxt; nxt = t;
    }

    gamma_kernel<<<B_N / 4, 256, 0, stream>>>(su, si, user_bias, item_bias,
                                              users, items, out);
}

// Round 6
// 714.553 us; speedup vs baseline: 8.9639x; 1.3125x over previous
//
#include <hip/hip_runtime.h>
#include <hip/hip_fp16.h>
#include <stdint.h>

#define U_N 100000
#define I_N 50000
#define D_DIM 64
#define E_N 6400000
#define B_N 16384
#define N_N 150000
#define NB 1024          // buckets
#define BKN 147          // nodes per bucket: ceil(150000/1024)
#define CAP 8192         // phaseB LDS record capacity (64KB)

typedef unsigned long long ull;

// ---------- convert concat(user_emb,item_emb) -> fp16 table ----------
__global__ __launch_bounds__(256) void to_half(const float2* __restrict__ ue,
                                               const float2* __restrict__ ie,
                                               __half2* __restrict__ h) {
    const int n2 = N_N * D_DIM / 2;
    const int u2 = U_N * D_DIM / 2;
    for (int i = blockIdx.x * blockDim.x + threadIdx.x; i < n2;
         i += gridDim.x * blockDim.x) {
        float2 x = (i < u2) ? ue[i] : ie[i - u2];
        h[i] = __floats2half2_rn(x.x, x.y);
    }
}

// ---------- bucket histogram, LDS-privatized ----------
__global__ __launch_bounds__(256) void bhist(const int* __restrict__ dst,
                                             int* __restrict__ btot) {
    __shared__ int h[NB];
    for (int i = threadIdx.x; i < NB; i += 256) h[i] = 0;
    __syncthreads();
    int chunk = (E_N + gridDim.x - 1) / gridDim.x;
    int beg = blockIdx.x * chunk;
    int end = min(E_N, beg + chunk);
    for (int e = beg + (int)threadIdx.x; e < end; e += 256)
        atomicAdd(&h[(unsigned)dst[e] / BKN], 1);
    __syncthreads();
    for (int i = threadIdx.x; i < NB; i += 256)
        if (h[i]) atomicAdd(&btot[i], h[i]);
}

// ---------- exclusive scan of 1024 bucket totals (one block) ----------
__global__ __launch_bounds__(NB) void scan_buckets(const int* __restrict__ btot,
                                                   int* __restrict__ bbase,
                                                   int* __restrict__ bcur,
                                                   int* __restrict__ row_ptr) {
    __shared__ int lds[NB];
    int t = threadIdx.x;
    int x = btot[t];
    lds[t] = x;
    __syncthreads();
    for (int off = 1; off < NB; off <<= 1) {
        int v = (t >= off) ? lds[t - off] : 0;
        __syncthreads();
        lds[t] += v;
        __syncthreads();
    }
    int excl = lds[t] - x;
    bbase[t] = excl;
    bcur[t] = excl;
    if (t == NB - 1) {
        bbase[NB] = lds[NB - 1];
        row_ptr[N_N] = lds[NB - 1];   // == E
    }
}

// ---------- phase A: block-privatized bucket partition ----------
// record = val(32) | dst_local(8) @bit18 | src(18)
__global__ __launch_bounds__(256) void phaseA(const int* __restrict__ src,
                                              const int* __restrict__ dst,
                                              const float* __restrict__ vals,
                                              int* __restrict__ bcur,
                                              ull* __restrict__ staging) {
    __shared__ int h[NB];
    __shared__ int base[NB];
    int chunk = (E_N + gridDim.x - 1) / gridDim.x;
    int beg = blockIdx.x * chunk;
    int end = min(E_N, beg + chunk);
    for (int i = threadIdx.x; i < NB; i += 256) h[i] = 0;
    __syncthreads();
    for (int e = beg + (int)threadIdx.x; e < end; e += 256)
        atomicAdd(&h[(unsigned)dst[e] / BKN], 1);
    __syncthreads();
    for (int i = threadIdx.x; i < NB; i += 256) {
        int c = h[i];
        base[i] = c ? atomicAdd(&bcur[i], c) : 0;
    }
    __syncthreads();
    for (int i = threadIdx.x; i < NB; i += 256) h[i] = 0;  // reuse as cursor
    __syncthreads();
    for (int e = beg + (int)threadIdx.x; e < end; e += 256) {
        unsigned d = (unsigned)dst[e];
        unsigned b = d / BKN;
        unsigned local = d - b * BKN;
        int pos = base[b] + atomicAdd(&h[b], 1);
        ull rec = ((ull)__float_as_uint(vals[e]) << 32)
                | ((ull)local << 18)
                | (ull)(unsigned)src[e];
        staging[pos] = rec;
    }
}

// ---------- phase B: one block per bucket; LDS-stage, sort, emit CSR+row_ptr ----------
__global__ __launch_bounds__(256) void phaseB(const ull* __restrict__ staging,
                                              const int* __restrict__ bbase,
                                              int2* __restrict__ csr,
                                              int* __restrict__ row_ptr) {
    __shared__ ull recs[CAP];
    __shared__ int hist[BKN];
    __shared__ int curs[BKN];
    int b = blockIdx.x;
    int beg = bbase[b];
    int cnt = bbase[b + 1] - beg;
    bool inlds = (cnt <= CAP);
    for (int i = threadIdx.x; i < BKN; i += 256) hist[i] = 0;
    __syncthreads();
    for (int i = threadIdx.x; i < cnt; i += 256) {
        ull rec = staging[beg + i];
        if (inlds) recs[i] = rec;
        atomicAdd(&hist[(int)((rec >> 18) & 0xFF)], 1);
    }
    __syncthreads();
    // wave 0: exclusive scan of 147 counts; write row_ptr + cursors
    if (threadIdx.x < 64) {
        int lane = threadIdx.x;
        int carry = 0;
        for (int c = 0; c < BKN; c += 64) {
            int i = c + lane;
            int x = (i < BKN) ? hist[i] : 0;
            int inc = x;
#pragma unroll
            for (int off = 1; off < 64; off <<= 1) {
                int v = __shfl_up(inc, off, 64);
                if (lane >= off) inc += v;
            }
            int excl = carry + inc - x;
            if (i < BKN) {
                int node = b * BKN + i;
                if (node < N_N) row_ptr[node] = beg + excl;
                curs[i] = excl;
            }
            carry += __shfl(inc, 63, 64);
        }
    }
    __syncthreads();
    for (int i = threadIdx.x; i < cnt; i += 256) {
        ull rec = inlds ? recs[i] : staging[beg + i];
        int local = (int)((rec >> 18) & 0xFF);
        int pos = atomicAdd(&curs[local], 1);
        csr[beg + pos] = make_int2((int)(rec & 0x3FFFFull), (int)(rec >> 32));
    }
}

// ---------- SpMM pull on fp16 table: one wave per row, 16-deep staged gathers ----------
__global__ __launch_bounds__(256) void spmm16(const __half* __restrict__ ecur,
                                              __half* __restrict__ enext,
                                              const int* __restrict__ row_ptr,
                                              const int2* __restrict__ csr) {
    int row = blockIdx.x * 4 + (threadIdx.x >> 6);
    int lane = threadIdx.x & 63;
    if (row >= N_N) return;
    int beg = row_ptr[row];
    int end = row_ptr[row + 1];
    float acc = 0.0f;
    for (int base = beg; base < end; base += 64) {
        // masked lanes get (0,0): s=0 is a safe gather, v=0 contributes nothing
        int2 rec = (base + lane < end) ? csr[base + lane] : make_int2(0, 0);
        int cnt = min(64, end - base);
        for (int j0 = 0; j0 < cnt; j0 += 16) {
            __half g[16];
            float v[16];
#pragma unroll
            for (int k = 0; k < 16; ++k) {
                int s = __shfl(rec.x, j0 + k, 64);
                v[k] = __int_as_float(__shfl(rec.y, j0 + k, 64));
                g[k] = ecur[(size_t)s * D_DIM + lane];   // 16 independent 128B gathers
            }
#pragma unroll
            for (int k = 0; k < 16; ++k)
                acc += v[k] * __half2float(g[k]);
        }
    }
    enext[(size_t)row * D_DIM + lane] = __float2half(acc);
}

// ---------- layer-0 accumulate from fp32 originals ----------
__global__ __launch_bounds__(256) void accum_f32(const float* __restrict__ ue,
                                                 const float* __restrict__ ie,
                                                 const int* __restrict__ users,
                                                 const int* __restrict__ items,
                                                 float* __restrict__ su,
                                                 float* __restrict__ si) {
    int r = blockIdx.x * 4 + (threadIdx.x >> 6);
    int lane = threadIdx.x & 63;
    if (r >= 2 * B_N) return;
    if (r < B_N) {
        su[(size_t)r * D_DIM + lane] += ue[(size_t)users[r] * D_DIM + lane];
    } else {
        int q = r - B_N;
        si[(size_t)q * D_DIM + lane] += ie[(size_t)items[q] * D_DIM + lane];
    }
}

// ---------- layer accumulate from fp16 table ----------
__global__ __launch_bounds__(256) void accum_h16(const __half* __restrict__ emb,
                                                 const int* __restrict__ users,
                                                 const int* __restrict__ items,
                                                 float* __restrict__ su,
                                                 float* __restrict__ si) {
    int r = blockIdx.x * 4 + (threadIdx.x >> 6);
    int lane = threadIdx.x & 63;
    if (r >= 2 * B_N) return;
    if (r < B_N) {
        su[(size_t)r * D_DIM + lane] +=
            __half2float(emb[(size_t)users[r] * D_DIM + lane]);
    } else {
        int q = r - B_N;
        si[(size_t)q * D_DIM + lane] +=
            __half2float(emb[((size_t)U_N + items[q]) * D_DIM + lane]);
    }
}

// ---------- gamma = su.si/16 + 64*(ub+ib) ----------
__global__ __launch_bounds__(256) void gamma_kernel(const float* __restrict__ su,
                                                    const float* __restrict__ si,
                                                    const float* __restrict__ ub,
                                                    const float* __restrict__ ib,
                                                    const int* __restrict__ users,
                                                    const int* __restrict__ items,
                                                    float* __restrict__ out) {
    int b = blockIdx.x * 4 + (threadIdx.x >> 6);
    int lane = threadIdx.x & 63;
    if (b >= B_N) return;
    float p = su[(size_t)b * D_DIM + lane] * si[(size_t)b * D_DIM + lane];
#pragma unroll
    for (int off = 32; off > 0; off >>= 1) p += __shfl_xor(p, off, 64);
    if (lane == 0) {
        float bias = ub[users[b]] + ib[items[b]];
        out[b] = p * (1.0f / 16.0f) + 64.0f * bias;
    }
}

extern "C" void kernel_launch(void* const* d_in, const int* in_sizes, int n_in,
                              void* d_out, int out_size, void* d_ws, size_t ws_size,
                              hipStream_t stream) {
    const float* user_emb  = (const float*)d_in[0];
    const float* item_emb  = (const float*)d_in[1];
    const float* user_bias = (const float*)d_in[2];
    const float* item_bias = (const float*)d_in[3];
    const float* vals      = (const float*)d_in[4];
    const int*   src       = (const int*)d_in[5];
    const int*   dst       = (const int*)d_in[6];
    const int*   users     = (const int*)d_in[7];
    const int*   items     = (const int*)d_in[8];
    float* out = (float*)d_out;

    char* ws = (char*)d_ws;
    size_t off = 0;
    auto alloc = [&](size_t bytes) -> void* {
        void* p = ws + off;
        off += (bytes + 255) & ~(size_t)255;
        return p;
    };
    __half* hA     = (__half*)alloc(sizeof(__half) * (size_t)N_N * D_DIM);  // 19.2MB
    __half* hB     = (__half*)alloc(sizeof(__half) * (size_t)N_N * D_DIM);  // 19.2MB
    float* su      = (float*)alloc(sizeof(float) * (size_t)B_N * D_DIM);    // 4.2MB
    float* si      = (float*)alloc(sizeof(float) * (size_t)B_N * D_DIM);    // 4.2MB
    int*   row_ptr = (int*)alloc(sizeof(int) * (N_N + 1));                  // 0.6MB
    int*   btot    = (int*)alloc(sizeof(int) * NB);
    int*   bbase   = (int*)alloc(sizeof(int) * (NB + 1));
    int*   bcur    = (int*)alloc(sizeof(int) * NB);
    int2*  csr     = (int2*)alloc(sizeof(int2) * (size_t)E_N);              // 51.2MB
    ull*   staging = (ull*)alloc(sizeof(ull) * (size_t)E_N);                // 51.2MB

    hipMemsetAsync(su, 0, sizeof(float) * (size_t)B_N * D_DIM * 2, stream);
    hipMemsetAsync(btot, 0, sizeof(int) * NB, stream);

    to_half<<<2048, 256, 0, stream>>>((const float2*)user_emb,
                                      (const float2*)item_emb, (__half2*)hA);
    bhist<<<512, 256, 0, stream>>>(dst, btot);
    scan_buckets<<<1, NB, 0, stream>>>(btot, bbase, bcur, row_ptr);
    phaseA<<<512, 256, 0, stream>>>(src, dst, vals, bcur, staging);
    phaseB<<<NB, 256, 0, stream>>>(staging, bbase, csr, row_ptr);

    // layer 0 contribution from fp32 originals
    accum_f32<<<(2 * B_N) / 4, 256, 0, stream>>>(user_emb, item_emb, users,
                                                 items, su, si);
    // layer 1: hA -> hB
    spmm16<<<(N_N + 3) / 4, 256, 0, stream>>>(hA, hB, row_ptr, csr);
    accum_h16<<<(2 * B_N) / 4, 256, 0, stream>>>(hB, users, items, su, si);
    // layer 2: hB -> hA
    spmm16<<<(N_N + 3) / 4, 256, 0, stream>>>(hB, hA, row_ptr, csr);
    accum_h16<<<(2 * B_N) / 4, 256, 0, stream>>>(hA, users, items, su, si);
    // layer 3: hA -> hB
    spmm16<<<(N_N + 3) / 4, 256, 0, stream>>>(hA, hB, row_ptr, csr);
    accum_h16<<<(2 * B_N) / 4, 256, 0, stream>>>(hB, users, items, su, si);

    gamma_kernel<<<B_N / 4, 256, 0, stream>>>(su, si, user_bias, item_bias,
                                              users, items, out);
}

// Round 7
// 552.051 us; speedup vs baseline: 11.6025x; 1.2944x over previous
//
#include <hip/hip_runtime.h>
#include <hip/hip_fp16.h>
#include <stdint.h>

#define U_N 100000
#define I_N 50000
#define D_DIM 64
#define E_N 6400000
#define B_N 16384
#define N_N 150000
#define NB 1024          // buckets
#define BKN 147          // nodes per bucket: ceil(150000/1024)
#define CAP 8192         // phaseB LDS record capacity (64KB)

typedef unsigned long long ull;

// ---------- convert concat(user_emb,item_emb) -> fp16 table ----------
__global__ __launch_bounds__(256) void to_half(const float2* __restrict__ ue,
                                               const float2* __restrict__ ie,
                                               __half2* __restrict__ h) {
    const int n2 = N_N * D_DIM / 2;
    const int u2 = U_N * D_DIM / 2;
    for (int i = blockIdx.x * blockDim.x + threadIdx.x; i < n2;
         i += gridDim.x * blockDim.x) {
        float2 x = (i < u2) ? ue[i] : ie[i - u2];
        h[i] = __floats2half2_rn(x.x, x.y);
    }
}

// ---------- bucket histogram, LDS-privatized ----------
__global__ __launch_bounds__(256) void bhist(const int* __restrict__ dst,
                                             int* __restrict__ btot) {
    __shared__ int h[NB];
    for (int i = threadIdx.x; i < NB; i += 256) h[i] = 0;
    __syncthreads();
    int chunk = (E_N + gridDim.x - 1) / gridDim.x;
    int beg = blockIdx.x * chunk;
    int end = min(E_N, beg + chunk);
    for (int e = beg + (int)threadIdx.x; e < end; e += 256)
        atomicAdd(&h[(unsigned)dst[e] / BKN], 1);
    __syncthreads();
    for (int i = threadIdx.x; i < NB; i += 256)
        if (h[i]) atomicAdd(&btot[i], h[i]);
}

// ---------- exclusive scan of 1024 bucket totals (one block) ----------
__global__ __launch_bounds__(NB) void scan_buckets(const int* __restrict__ btot,
                                                   int* __restrict__ bbase,
                                                   int* __restrict__ bcur,
                                                   int* __restrict__ row_ptr) {
    __shared__ int lds[NB];
    int t = threadIdx.x;
    int x = btot[t];
    lds[t] = x;
    __syncthreads();
    for (int off = 1; off < NB; off <<= 1) {
        int v = (t >= off) ? lds[t - off] : 0;
        __syncthreads();
        lds[t] += v;
        __syncthreads();
    }
    int excl = lds[t] - x;
    bbase[t] = excl;
    bcur[t] = excl;
    if (t == NB - 1) {
        bbase[NB] = lds[NB - 1];
        row_ptr[N_N] = lds[NB - 1];   // == E
    }
}

// ---------- phase A: block-privatized bucket partition ----------
// record = val(32) | dst_local(8) @bit18 | src(18)
__global__ __launch_bounds__(256) void phaseA(const int* __restrict__ src,
                                              const int* __restrict__ dst,
                                              const float* __restrict__ vals,
                                              int* __restrict__ bcur,
                                              ull* __restrict__ staging) {
    __shared__ int h[NB];
    __shared__ int base[NB];
    int chunk = (E_N + gridDim.x - 1) / gridDim.x;
    int beg = blockIdx.x * chunk;
    int end = min(E_N, beg + chunk);
    for (int i = threadIdx.x; i < NB; i += 256) h[i] = 0;
    __syncthreads();
    for (int e = beg + (int)threadIdx.x; e < end; e += 256)
        atomicAdd(&h[(unsigned)dst[e] / BKN], 1);
    __syncthreads();
    for (int i = threadIdx.x; i < NB; i += 256) {
        int c = h[i];
        base[i] = c ? atomicAdd(&bcur[i], c) : 0;
    }
    __syncthreads();
    for (int i = threadIdx.x; i < NB; i += 256) h[i] = 0;  // reuse as cursor
    __syncthreads();
    for (int e = beg + (int)threadIdx.x; e < end; e += 256) {
        unsigned d = (unsigned)dst[e];
        unsigned b = d / BKN;
        unsigned local = d - b * BKN;
        int pos = base[b] + atomicAdd(&h[b], 1);
        ull rec = ((ull)__float_as_uint(vals[e]) << 32)
                | ((ull)local << 18)
                | (ull)(unsigned)src[e];
        staging[pos] = rec;
    }
}

// ---------- phase B: one block per bucket; LDS-stage, sort, emit CSR+row_ptr ----------
__global__ __launch_bounds__(256) void phaseB(const ull* __restrict__ staging,
                                              const int* __restrict__ bbase,
                                              int2* __restrict__ csr,
                                              int* __restrict__ row_ptr) {
    __shared__ ull recs[CAP];
    __shared__ int hist[BKN];
    __shared__ int curs[BKN];
    int b = blockIdx.x;
    int beg = bbase[b];
    int cnt = bbase[b + 1] - beg;
    bool inlds = (cnt <= CAP);
    for (int i = threadIdx.x; i < BKN; i += 256) hist[i] = 0;
    __syncthreads();
    for (int i = threadIdx.x; i < cnt; i += 256) {
        ull rec = staging[beg + i];
        if (inlds) recs[i] = rec;
        atomicAdd(&hist[(int)((rec >> 18) & 0xFF)], 1);
    }
    __syncthreads();
    // wave 0: exclusive scan of 147 counts; write row_ptr + cursors
    if (threadIdx.x < 64) {
        int lane = threadIdx.x;
        int carry = 0;
        for (int c = 0; c < BKN; c += 64) {
            int i = c + lane;
            int x = (i < BKN) ? hist[i] : 0;
            int inc = x;
#pragma unroll
            for (int off = 1; off < 64; off <<= 1) {
                int v = __shfl_up(inc, off, 64);
                if (lane >= off) inc += v;
            }
            int excl = carry + inc - x;
            if (i < BKN) {
                int node = b * BKN + i;
                if (node < N_N) row_ptr[node] = beg + excl;
                curs[i] = excl;
            }
            carry += __shfl(inc, 63, 64);
        }
    }
    __syncthreads();
    for (int i = threadIdx.x; i < cnt; i += 256) {
        ull rec = inlds ? recs[i] : staging[beg + i];
        int local = (int)((rec >> 18) & 0xFF);
        int pos = atomicAdd(&curs[local], 1);
        csr[beg + pos] = make_int2((int)(rec & 0x3FFFFull), (int)(rec >> 32));
    }
}

// ---------- SpMM pull on fp16 table: 2 edges/instruction, LDS record broadcast ----------
// lanes 0-31 process even edge slot, lanes 32-63 the odd slot; each lane gathers
// a half2 (2 columns). One ds_read_b64 replaces 2 ds_bpermute per edge.
__global__ __launch_bounds__(256) void spmm16(const __half2* __restrict__ ecur,
                                              __half2* __restrict__ enext,
                                              const int* __restrict__ row_ptr,
                                              const int2* __restrict__ csr) {
    __shared__ int2 recs[4][64];
    const int wid = threadIdx.x >> 6;
    const int lane = threadIdx.x & 63;
    const int half = lane >> 5;      // which edge of the pair
    const int col = lane & 31;       // half2 column
    int row = blockIdx.x * 4 + wid;
    if (row >= N_N) return;
    int beg = row_ptr[row];
    int end = row_ptr[row + 1];
    float accx = 0.f, accy = 0.f;

    for (int base = beg; base < end; base += 64) {
        // coalesced batch load; masked slots zero (s=0 safe gather, v=0)
        int2 rec = (base + lane < end) ? csr[base + lane] : make_int2(0, 0);
        recs[wid][lane] = rec;       // wave-private LDS, in-order DS pipe
        int cnt = min(64, end - base);
        int j0 = 0;
        for (; j0 + 32 <= cnt; j0 += 32) {          // K16: 32 edges, 16 gathers in flight
            unsigned g[16];
            float v[16];
#pragma unroll
            for (int k = 0; k < 16; ++k) {
                int2 r = recs[wid][j0 + 2 * k + half];   // ds_read_b64 broadcast
                v[k] = __int_as_float(r.y);
                g[k] = *(const unsigned*)(ecur + (size_t)r.x * 32 + col);
            }
#pragma unroll
            for (int k = 0; k < 16; ++k) {
                __half2 h = *(__half2*)&g[k];
                accx += __low2float(h) * v[k];      // v_fma_mix_f32
                accy += __high2float(h) * v[k];
            }
        }
        for (; j0 < cnt; j0 += 16) {                // K8 tail: 16 edges
            unsigned g[8];
            float v[8];
#pragma unroll
            for (int k = 0; k < 8; ++k) {
                int2 r = recs[wid][j0 + 2 * k + half];
                v[k] = __int_as_float(r.y);
                g[k] = *(const unsigned*)(ecur + (size_t)r.x * 32 + col);
            }
#pragma unroll
            for (int k = 0; k < 8; ++k) {
                __half2 h = *(__half2*)&g[k];
                accx += __low2float(h) * v[k];
                accy += __high2float(h) * v[k];
            }
        }
    }
    // fold the two edge-halves (both halves hold partial sums of same cols)
    accx += __shfl_xor(accx, 32, 64);
    accy += __shfl_xor(accy, 32, 64);
    if (lane < 32)
        enext[(size_t)row * 32 + col] = __floats2half2_rn(accx, accy);
}

// ---------- layer-0 accumulate from fp32 originals ----------
__global__ __launch_bounds__(256) void accum_f32(const float* __restrict__ ue,
                                                 const float* __restrict__ ie,
                                                 const int* __restrict__ users,
                                                 const int* __restrict__ items,
                                                 float* __restrict__ su,
                                                 float* __restrict__ si) {
    int r = blockIdx.x * 4 + (threadIdx.x >> 6);
    int lane = threadIdx.x & 63;
    if (r >= 2 * B_N) return;
    if (r < B_N) {
        su[(size_t)r * D_DIM + lane] += ue[(size_t)users[r] * D_DIM + lane];
    } else {
        int q = r - B_N;
        si[(size_t)q * D_DIM + lane] += ie[(size_t)items[q] * D_DIM + lane];
    }
}

// ---------- layer accumulate from fp16 table ----------
__global__ __launch_bounds__(256) void accum_h16(const __half* __restrict__ emb,
                                                 const int* __restrict__ users,
                                                 const int* __restrict__ items,
                                                 float* __restrict__ su,
                                                 float* __restrict__ si) {
    int r = blockIdx.x * 4 + (threadIdx.x >> 6);
    int lane = threadIdx.x & 63;
    if (r >= 2 * B_N) return;
    if (r < B_N) {
        su[(size_t)r * D_DIM + lane] +=
            __half2float(emb[(size_t)users[r] * D_DIM + lane]);
    } else {
        int q = r - B_N;
        si[(size_t)q * D_DIM + lane] +=
            __half2float(emb[((size_t)U_N + items[q]) * D_DIM + lane]);
    }
}

// ---------- gamma = su.si/16 + 64*(ub+ib) ----------
__global__ __launch_bounds__(256) void gamma_kernel(const float* __restrict__ su,
                                                    const float* __restrict__ si,
                                                    const float* __restrict__ ub,
                                                    const float* __restrict__ ib,
                                                    const int* __restrict__ users,
                                                    const int* __restrict__ items,
                                                    float* __restrict__ out) {
    int b = blockIdx.x * 4 + (threadIdx.x >> 6);
    int lane = threadIdx.x & 63;
    if (b >= B_N) return;
    float p = su[(size_t)b * D_DIM + lane] * si[(size_t)b * D_DIM + lane];
#pragma unroll
    for (int off = 32; off > 0; off >>= 1) p += __shfl_xor(p, off, 64);
    if (lane == 0) {
        float bias = ub[users[b]] + ib[items[b]];
        out[b] = p * (1.0f / 16.0f) + 64.0f * bias;
    }
}

extern "C" void kernel_launch(void* const* d_in, const int* in_sizes, int n_in,
                              void* d_out, int out_size, void* d_ws, size_t ws_size,
                              hipStream_t stream) {
    const float* user_emb  = (const float*)d_in[0];
    const float* item_emb  = (const float*)d_in[1];
    const float* user_bias = (const float*)d_in[2];
    const float* item_bias = (const float*)d_in[3];
    const float* vals      = (const float*)d_in[4];
    const int*   src       = (const int*)d_in[5];
    const int*   dst       = (const int*)d_in[6];
    const int*   users     = (const int*)d_in[7];
    const int*   items     = (const int*)d_in[8];
    float* out = (float*)d_out;

    char* ws = (char*)d_ws;
    size_t off = 0;
    auto alloc = [&](size_t bytes) -> void* {
        void* p = ws + off;
        off += (bytes + 255) & ~(size_t)255;
        return p;
    };
    __half* hA     = (__half*)alloc(sizeof(__half) * (size_t)N_N * D_DIM);  // 19.2MB
    __half* hB     = (__half*)alloc(sizeof(__half) * (size_t)N_N * D_DIM);  // 19.2MB
    float* su      = (float*)alloc(sizeof(float) * (size_t)B_N * D_DIM);    // 4.2MB
    float* si      = (float*)alloc(sizeof(float) * (size_t)B_N * D_DIM);    // 4.2MB
    int*   row_ptr = (int*)alloc(sizeof(int) * (N_N + 1));                  // 0.6MB
    int*   btot    = (int*)alloc(sizeof(int) * NB);
    int*   bbase   = (int*)alloc(sizeof(int) * (NB + 1));
    int*   bcur    = (int*)alloc(sizeof(int) * NB);
    int2*  csr     = (int2*)alloc(sizeof(int2) * (size_t)E_N);              // 51.2MB
    ull*   staging = (ull*)alloc(sizeof(ull) * (size_t)E_N);                // 51.2MB

    hipMemsetAsync(su, 0, sizeof(float) * (size_t)B_N * D_DIM * 2, stream);
    hipMemsetAsync(btot, 0, sizeof(int) * NB, stream);

    to_half<<<2048, 256, 0, stream>>>((const float2*)user_emb,
                                      (const float2*)item_emb, (__half2*)hA);
    bhist<<<512, 256, 0, stream>>>(dst, btot);
    scan_buckets<<<1, NB, 0, stream>>>(btot, bbase, bcur, row_ptr);
    phaseA<<<512, 256, 0, stream>>>(src, dst, vals, bcur, staging);
    phaseB<<<NB, 256, 0, stream>>>(staging, bbase, csr, row_ptr);

    // layer 0 contribution from fp32 originals
    accum_f32<<<(2 * B_N) / 4, 256, 0, stream>>>(user_emb, item_emb, users,
                                                 items, su, si);
    // layer 1: hA -> hB
    spmm16<<<(N_N + 3) / 4, 256, 0, stream>>>((const __half2*)hA, (__half2*)hB,
                                              row_ptr, csr);
    accum_h16<<<(2 * B_N) / 4, 256, 0, stream>>>(hB, users, items, su, si);
    // layer 2: hB -> hA
    spmm16<<<(N_N + 3) / 4, 256, 0, stream>>>((const __half2*)hB, (__half2*)hA,
                                              row_ptr, csr);
    accum_h16<<<(2 * B_N) / 4, 256, 0, stream>>>(hA, users, items, su, si);
    // layer 3: hA -> hB
    spmm16<<<(N_N + 3) / 4, 256, 0, stream>>>((const __half2*)hA, (__half2*)hB,
                                              row_ptr, csr);
    accum_h16<<<(2 * B_N) / 4, 256, 0, stream>>>(hB, users, items, su, si);

    gamma_kernel<<<B_N / 4, 256, 0, stream>>>(su, si, user_bias, item_bias,
                                              users, items, out);
}

// Round 8
// 488.537 us; speedup vs baseline: 13.1109x; 1.1300x over previous
//
#include <hip/hip_runtime.h>
#include <hip/hip_fp16.h>
#include <stdint.h>

#define U_N 100000
#define I_N 50000
#define D_DIM 64
#define E_N 6400000
#define B_N 16384
#define N_N 150000
#define BKN 128            // nodes per bucket (power of 2: bucket = dst>>7)
#define NB 1172            // ceil(150000/128)
#define CAPB 6144          // per-bucket slot capacity (lambda=5461, +9 sigma)
#define CHUNK_A 6250       // edges per phaseA block (1024 blocks exactly)
#define PAIRS 586          // NB/2

typedef unsigned long long ull;

// ---------- convert concat(user_emb,item_emb) -> fp16 table ----------
__global__ __launch_bounds__(256) void to_half(const float2* __restrict__ ue,
                                               const float2* __restrict__ ie,
                                               __half2* __restrict__ h) {
    const int n2 = N_N * D_DIM / 2;
    const int u2 = U_N * D_DIM / 2;
    for (int i = blockIdx.x * blockDim.x + threadIdx.x; i < n2;
         i += gridDim.x * blockDim.x) {
        float2 x = (i < u2) ? ue[i] : ie[i - u2];
        h[i] = __floats2half2_rn(x.x, x.y);
    }
}

// ---------- phase A: per-block counting sort into LDS, coalesced sweep out ----------
// record (52 bits): val_fp16<<36 | dst18<<18 | src18
__global__ __launch_bounds__(1024) void phaseA(const int* __restrict__ src,
                                               const int* __restrict__ dst,
                                               const float* __restrict__ vals,
                                               int* __restrict__ bcur,
                                               ull* __restrict__ staging) {
    __shared__ int hist[NB];     // counts -> excl bases -> running cursors
    __shared__ int delta[NB];    // global_pos = delta[b] + lds_index
    __shared__ ull recs[CHUNK_A];
    __shared__ int wsum[10];
    const int tid = threadIdx.x;
    const int beg = blockIdx.x * CHUNK_A;

    for (int i = tid; i < NB; i += 1024) hist[i] = 0;
    __syncthreads();
    // pass 1: bucket histogram
    for (int e = tid; e < CHUNK_A; e += 1024)
        atomicAdd(&hist[((unsigned)dst[beg + e]) >> 7], 1);
    __syncthreads();

    // exclusive scan of hist[NB]: 2 entries per thread, wave scan + wave-total scan
    int e0 = 0, e1 = 0, s = 0;
    if (tid < PAIRS) { e0 = hist[2 * tid]; e1 = hist[2 * tid + 1]; s = e0 + e1; }
    int incl = s;
#pragma unroll
    for (int off = 1; off < 64; off <<= 1) {
        int v = __shfl_up(incl, off, 64);
        if ((tid & 63) >= off) incl += v;
    }
    if ((tid & 63) == 63 && (tid >> 6) < 10) wsum[tid >> 6] = incl;
    __syncthreads();
    if (tid == 0) {
        int run = 0;
        for (int w = 0; w < 10; ++w) { int t = wsum[w]; wsum[w] = run; run += t; }
    }
    __syncthreads();
    if (tid < PAIRS) {
        int excl = wsum[tid >> 6] + incl - s;       // base of bucket 2*tid
        int b0 = 2 * tid, b1 = 2 * tid + 1;
        int g0 = e0 ? atomicAdd(&bcur[b0], e0) : 0; // reserve global slots
        int g1 = e1 ? atomicAdd(&bcur[b1], e1) : 0;
        delta[b0] = b0 * CAPB + g0 - excl;
        delta[b1] = b1 * CAPB + g1 - (excl + e0);
        hist[b0] = excl;                            // cursor init
        hist[b1] = excl + e0;
    }
    __syncthreads();

    // pass 2: scatter records into LDS, sorted by bucket
    for (int e = tid; e < CHUNK_A; e += 1024) {
        int d = dst[beg + e];
        unsigned b = ((unsigned)d) >> 7;
        unsigned short hb = __half_as_ushort(__float2half(vals[beg + e]));
        ull rec = ((ull)hb << 36) | ((ull)(unsigned)d << 18)
                | (ull)(unsigned)src[beg + e];
        int lpos = atomicAdd(&hist[b], 1);
        recs[lpos] = rec;
    }
    __syncthreads();

    // sweep: consecutive lanes -> consecutive global addrs within bucket runs
    for (int i = tid; i < CHUNK_A; i += 1024) {
        ull rec = recs[i];
        unsigned d = (unsigned)(rec >> 18) & 0x3FFFFu;
        unsigned b = d >> 7;
        staging[(size_t)(delta[b] + i)] = rec;
    }
}

// ---------- phase B: one block per bucket; sort by node, emit split CSR ----------
__global__ __launch_bounds__(256) void phaseB(const ull* __restrict__ staging,
                                              const int* __restrict__ bcur,
                                              unsigned* __restrict__ csr_src,
                                              __half* __restrict__ csr_val,
                                              int* __restrict__ row_ptr,
                                              unsigned short* __restrict__ row_len) {
    __shared__ ull recs[CAPB];       // 48KB
    __shared__ int hist[BKN];
    __shared__ int curs[BKN];
    const int b = blockIdx.x;
    const int cnt = bcur[b];
    const int sbase = b * CAPB;
    for (int i = threadIdx.x; i < BKN; i += 256) hist[i] = 0;
    __syncthreads();
    for (int i = threadIdx.x; i < cnt; i += 256) {
        ull rec = staging[sbase + i];
        recs[i] = rec;
        atomicAdd(&hist[(int)((rec >> 18) & 0x7Fu)], 1);
    }
    __syncthreads();
    // wave 0: exclusive scan of 128 counts; write row_ptr/row_len + cursors
    if (threadIdx.x < 64) {
        int lane = threadIdx.x;
        int carry = 0;
#pragma unroll
        for (int c = 0; c < BKN; c += 64) {
            int x = hist[c + lane];
            int inc = x;
#pragma unroll
            for (int off = 1; off < 64; off <<= 1) {
                int v = __shfl_up(inc, off, 64);
                if (lane >= off) inc += v;
            }
            int excl = carry + inc - x;
            int node = b * BKN + c + lane;
            if (node < N_N) {
                row_ptr[node] = sbase + excl;
                row_len[node] = (unsigned short)x;
            }
            curs[c + lane] = excl;
            carry += __shfl(inc, 63, 64);
        }
    }
    __syncthreads();
    for (int i = threadIdx.x; i < cnt; i += 256) {
        ull rec = recs[i];
        int local = (int)((rec >> 18) & 0x7Fu);
        int pos = sbase + atomicAdd(&curs[local], 1);
        csr_src[pos] = (unsigned)(rec & 0x3FFFFu);
        csr_val[pos] = __ushort_as_half((unsigned short)(rec >> 36));
    }
}

// ---------- SpMM pull on fp16 table: 2 edges/instruction, LDS record broadcast ----------
__global__ __launch_bounds__(256) void spmm16(const __half2* __restrict__ ecur,
                                              __half2* __restrict__ enext,
                                              const int* __restrict__ row_ptr,
                                              const unsigned short* __restrict__ row_len,
                                              const unsigned* __restrict__ csr_src,
                                              const __half* __restrict__ csr_val) {
    __shared__ int2 recs[4][64];
    const int wid = threadIdx.x >> 6;
    const int lane = threadIdx.x & 63;
    const int hlf = lane >> 5;       // which edge of the pair
    const int col = lane & 31;       // half2 column
    int row = blockIdx.x * 4 + wid;
    if (row >= N_N) return;
    int beg = row_ptr[row];
    int end = beg + row_len[row];
    float accx = 0.f, accy = 0.f;

    for (int base = beg; base < end; base += 64) {
        int2 rec;
        if (base + lane < end) {
            rec.x = (int)csr_src[base + lane];
            rec.y = __float_as_int(__half2float(csr_val[base + lane]));
        } else {
            rec = make_int2(0, 0);   // s=0 safe gather, v=0 contributes nothing
        }
        recs[wid][lane] = rec;       // wave-private LDS, in-order DS pipe
        int cnt = min(64, end - base);
        int j0 = 0;
        for (; j0 + 32 <= cnt; j0 += 32) {          // 32 edges, 16 gathers in flight
            unsigned g[16];
            float v[16];
#pragma unroll
            for (int k = 0; k < 16; ++k) {
                int2 r = recs[wid][j0 + 2 * k + hlf];
                v[k] = __int_as_float(r.y);
                g[k] = *(const unsigned*)(ecur + (size_t)r.x * 32 + col);
            }
#pragma unroll
            for (int k = 0; k < 16; ++k) {
                __half2 h = *(__half2*)&g[k];
                accx += __low2float(h) * v[k];
                accy += __high2float(h) * v[k];
            }
        }
        for (; j0 < cnt; j0 += 16) {                // 16-edge tail
            unsigned g[8];
            float v[8];
#pragma unroll
            for (int k = 0; k < 8; ++k) {
                int2 r = recs[wid][j0 + 2 * k + hlf];
                v[k] = __int_as_float(r.y);
                g[k] = *(const unsigned*)(ecur + (size_t)r.x * 32 + col);
            }
#pragma unroll
            for (int k = 0; k < 8; ++k) {
                __half2 h = *(__half2*)&g[k];
                accx += __low2float(h) * v[k];
                accy += __high2float(h) * v[k];
            }
        }
    }
    accx += __shfl_xor(accx, 32, 64);
    accy += __shfl_xor(accy, 32, 64);
    if (lane < 32)
        enext[(size_t)row * 32 + col] = __floats2half2_rn(accx, accy);
}

// ---------- layer-0 accumulate from fp32 originals ----------
__global__ __launch_bounds__(256) void accum_f32(const float* __restrict__ ue,
                                                 const float* __restrict__ ie,
                                                 const int* __restrict__ users,
                                                 const int* __restrict__ items,
                                                 float* __restrict__ su,
                                                 float* __restrict__ si) {
    int r = blockIdx.x * 4 + (threadIdx.x >> 6);
    int lane = threadIdx.x & 63;
    if (r >= 2 * B_N) return;
    if (r < B_N) {
        su[(size_t)r * D_DIM + lane] += ue[(size_t)users[r] * D_DIM + lane];
    } else {
        int q = r - B_N;
        si[(size_t)q * D_DIM + lane] += ie[(size_t)items[q] * D_DIM + lane];
    }
}

// ---------- layer accumulate from fp16 table ----------
__global__ __launch_bounds__(256) void accum_h16(const __half* __restrict__ emb,
                                                 const int* __restrict__ users,
                                                 const int* __restrict__ items,
                                                 float* __restrict__ su,
                                                 float* __restrict__ si) {
    int r = blockIdx.x * 4 + (threadIdx.x >> 6);
    int lane = threadIdx.x & 63;
    if (r >= 2 * B_N) return;
    if (r < B_N) {
        su[(size_t)r * D_DIM + lane] +=
            __half2float(emb[(size_t)users[r] * D_DIM + lane]);
    } else {
        int q = r - B_N;
        si[(size_t)q * D_DIM + lane] +=
            __half2float(emb[((size_t)U_N + items[q]) * D_DIM + lane]);
    }
}

// ---------- gamma = su.si/16 + 64*(ub+ib) ----------
__global__ __launch_bounds__(256) void gamma_kernel(const float* __restrict__ su,
                                                    const float* __restrict__ si,
                                                    const float* __restrict__ ub,
                                                    const float* __restrict__ ib,
                                                    const int* __restrict__ users,
                                                    const int* __restrict__ items,
                                                    float* __restrict__ out) {
    int b = blockIdx.x * 4 + (threadIdx.x >> 6);
    int lane = threadIdx.x & 63;
    if (b >= B_N) return;
    float p = su[(size_t)b * D_DIM + lane] * si[(size_t)b * D_DIM + lane];
#pragma unroll
    for (int off = 32; off > 0; off >>= 1) p += __shfl_xor(p, off, 64);
    if (lane == 0) {
        float bias = ub[users[b]] + ib[items[b]];
        out[b] = p * (1.0f / 16.0f) + 64.0f * bias;
    }
}

extern "C" void kernel_launch(void* const* d_in, const int* in_sizes, int n_in,
                              void* d_out, int out_size, void* d_ws, size_t ws_size,
                              hipStream_t stream) {
    const float* user_emb  = (const float*)d_in[0];
    const float* item_emb  = (const float*)d_in[1];
    const float* user_bias = (const float*)d_in[2];
    const float* item_bias = (const float*)d_in[3];
    const float* vals      = (const float*)d_in[4];
    const int*   src       = (const int*)d_in[5];
    const int*   dst       = (const int*)d_in[6];
    const int*   users     = (const int*)d_in[7];
    const int*   items     = (const int*)d_in[8];
    float* out = (float*)d_out;

    char* ws = (char*)d_ws;
    size_t off = 0;
    auto alloc = [&](size_t bytes) -> void* {
        void* p = ws + off;
        off += (bytes + 255) & ~(size_t)255;
        return p;
    };
    const size_t SLOTS = (size_t)NB * CAPB;                                   // 7.2M
    __half* hA      = (__half*)alloc(sizeof(__half) * (size_t)N_N * D_DIM);   // 19.2MB
    __half* hB      = (__half*)alloc(sizeof(__half) * (size_t)N_N * D_DIM);   // 19.2MB
    float*  su      = (float*)alloc(sizeof(float) * (size_t)B_N * D_DIM);     // 4.2MB
    float*  si      = (float*)alloc(sizeof(float) * (size_t)B_N * D_DIM);     // 4.2MB
    int*    row_ptr = (int*)alloc(sizeof(int) * N_N);                         // 0.6MB
    unsigned short* row_len = (unsigned short*)alloc(sizeof(short) * N_N);    // 0.3MB
    int*    bcur    = (int*)alloc(sizeof(int) * NB);
    ull*    staging = (ull*)alloc(sizeof(ull) * SLOTS);                       // 57.6MB
    unsigned* csr_src = (unsigned*)alloc(sizeof(unsigned) * SLOTS);           // 28.8MB
    __half* csr_val = (__half*)alloc(sizeof(__half) * SLOTS);                 // 14.4MB

    hipMemsetAsync(su, 0, sizeof(float) * (size_t)B_N * D_DIM * 2, stream);
    hipMemsetAsync(bcur, 0, sizeof(int) * NB, stream);

    to_half<<<2048, 256, 0, stream>>>((const float2*)user_emb,
                                      (const float2*)item_emb, (__half2*)hA);
    phaseA<<<1024, 1024, 0, stream>>>(src, dst, vals, bcur, staging);
    phaseB<<<NB, 256, 0, stream>>>(staging, bcur, csr_src, csr_val,
                                   row_ptr, row_len);

    // layer 0 contribution from fp32 originals
    accum_f32<<<(2 * B_N) / 4, 256, 0, stream>>>(user_emb, item_emb, users,
                                                 items, su, si);
    // layer 1: hA -> hB
    spmm16<<<(N_N + 3) / 4, 256, 0, stream>>>((const __half2*)hA, (__half2*)hB,
                                              row_ptr, row_len, csr_src, csr_val);
    accum_h16<<<(2 * B_N) / 4, 256, 0, stream>>>(hB, users, items, su, si);
    // layer 2: hB -> hA
    spmm16<<<(N_N + 3) / 4, 256, 0, stream>>>((const __half2*)hB, (__half2*)hA,
                                              row_ptr, row_len, csr_src, csr_val);
    accum_h16<<<(2 * B_N) / 4, 256, 0, stream>>>(hA, users, items, su, si);
    // layer 3: hA -> hB
    spmm16<<<(N_N + 3) / 4, 256, 0, stream>>>((const __half2*)hA, (__half2*)hB,
                                              row_ptr, row_len, csr_src, csr_val);
    accum_h16<<<(2 * B_N) / 4, 256, 0, stream>>>(hB, users, items, su, si);

    gamma_kernel<<<B_N / 4, 256, 0, stream>>>(su, si, user_bias, item_bias,
                                              users, items, out);
}

// Round 9
// 410.178 us; speedup vs baseline: 15.6156x; 1.1910x over previous
//
#include <hip/hip_runtime.h>
#include <hip/hip_fp16.h>
#include <stdint.h>

#define U_N 100000
#define I_N 50000
#define D_DIM 64
#define E_N 6400000
#define B_N 16384
#define N_N 150000
#define BKN 128            // nodes per bucket (power of 2: bucket = dst>>7)
#define NB 1172            // ceil(150000/128)
#define CAPB 6144          // per-bucket slot capacity (lambda=5461, +9 sigma)
#define CHUNK_A 6250       // edges per phaseA block (1024 blocks exactly)
#define PAIRS 586          // NB/2

typedef unsigned long long ull;

// ---------- convert concat(user_emb,item_emb) -> fp16 table ----------
__global__ __launch_bounds__(256) void to_half(const float2* __restrict__ ue,
                                               const float2* __restrict__ ie,
                                               __half2* __restrict__ h) {
    const int n2 = N_N * D_DIM / 2;
    const int u2 = U_N * D_DIM / 2;
    for (int i = blockIdx.x * blockDim.x + threadIdx.x; i < n2;
         i += gridDim.x * blockDim.x) {
        float2 x = (i < u2) ? ue[i] : ie[i - u2];
        h[i] = __floats2half2_rn(x.x, x.y);
    }
}

// ---------- phase A: per-block counting sort into LDS, coalesced sweep out ----------
// record (52 bits): val_fp16<<36 | dst18<<18 | src18
__global__ __launch_bounds__(1024) void phaseA(const int* __restrict__ src,
                                               const int* __restrict__ dst,
                                               const float* __restrict__ vals,
                                               int* __restrict__ bcur,
                                               ull* __restrict__ staging) {
    __shared__ int hist[NB];     // counts -> excl bases -> running cursors
    __shared__ int delta[NB];    // global_pos = delta[b] + lds_index
    __shared__ ull recs[CHUNK_A];
    __shared__ int wsum[10];
    const int tid = threadIdx.x;
    const int beg = blockIdx.x * CHUNK_A;

    for (int i = tid; i < NB; i += 1024) hist[i] = 0;
    __syncthreads();
    // pass 1: bucket histogram
    for (int e = tid; e < CHUNK_A; e += 1024)
        atomicAdd(&hist[((unsigned)dst[beg + e]) >> 7], 1);
    __syncthreads();

    // exclusive scan of hist[NB]: 2 entries per thread, wave scan + wave-total scan
    int e0 = 0, e1 = 0, s = 0;
    if (tid < PAIRS) { e0 = hist[2 * tid]; e1 = hist[2 * tid + 1]; s = e0 + e1; }
    int incl = s;
#pragma unroll
    for (int off = 1; off < 64; off <<= 1) {
        int v = __shfl_up(incl, off, 64);
        if ((tid & 63) >= off) incl += v;
    }
    if ((tid & 63) == 63 && (tid >> 6) < 10) wsum[tid >> 6] = incl;
    __syncthreads();
    if (tid == 0) {
        int run = 0;
        for (int w = 0; w < 10; ++w) { int t = wsum[w]; wsum[w] = run; run += t; }
    }
    __syncthreads();
    if (tid < PAIRS) {
        int excl = wsum[tid >> 6] + incl - s;       // base of bucket 2*tid
        int b0 = 2 * tid, b1 = 2 * tid + 1;
        int g0 = e0 ? atomicAdd(&bcur[b0], e0) : 0; // reserve global slots
        int g1 = e1 ? atomicAdd(&bcur[b1], e1) : 0;
        delta[b0] = b0 * CAPB + g0 - excl;
        delta[b1] = b1 * CAPB + g1 - (excl + e0);
        hist[b0] = excl;                            // cursor init
        hist[b1] = excl + e0;
    }
    __syncthreads();

    // pass 2: scatter records into LDS, sorted by bucket
    for (int e = tid; e < CHUNK_A; e += 1024) {
        int d = dst[beg + e];
        unsigned b = ((unsigned)d) >> 7;
        unsigned short hb = __half_as_ushort(__float2half(vals[beg + e]));
        ull rec = ((ull)hb << 36) | ((ull)(unsigned)d << 18)
                | (ull)(unsigned)src[beg + e];
        int lpos = atomicAdd(&hist[b], 1);
        recs[lpos] = rec;
    }
    __syncthreads();

    // sweep: consecutive lanes -> consecutive global addrs within bucket runs
    for (int i = tid; i < CHUNK_A; i += 1024) {
        ull rec = recs[i];
        unsigned d = (unsigned)(rec >> 18) & 0x3FFFFu;
        unsigned b = d >> 7;
        staging[(size_t)(delta[b] + i)] = rec;
    }
}

// ---------- phase B: one block per bucket; sort by node, emit split CSR ----------
// csr_src holds BYTE offsets into the fp16 table (src * 128)
__global__ __launch_bounds__(256) void phaseB(const ull* __restrict__ staging,
                                              const int* __restrict__ bcur,
                                              unsigned* __restrict__ csr_src,
                                              __half* __restrict__ csr_val,
                                              int* __restrict__ row_ptr,
                                              unsigned short* __restrict__ row_len) {
    __shared__ ull recs[CAPB];       // 48KB
    __shared__ int hist[BKN];
    __shared__ int curs[BKN];
    const int b = blockIdx.x;
    const int cnt = bcur[b];
    const int sbase = b * CAPB;
    for (int i = threadIdx.x; i < BKN; i += 256) hist[i] = 0;
    __syncthreads();
    for (int i = threadIdx.x; i < cnt; i += 256) {
        ull rec = staging[sbase + i];
        recs[i] = rec;
        atomicAdd(&hist[(int)((rec >> 18) & 0x7Fu)], 1);
    }
    __syncthreads();
    // wave 0: exclusive scan of 128 counts; write row_ptr/row_len + cursors
    if (threadIdx.x < 64) {
        int lane = threadIdx.x;
        int carry = 0;
#pragma unroll
        for (int c = 0; c < BKN; c += 64) {
            int x = hist[c + lane];
            int inc = x;
#pragma unroll
            for (int off = 1; off < 64; off <<= 1) {
                int v = __shfl_up(inc, off, 64);
                if (lane >= off) inc += v;
            }
            int excl = carry + inc - x;
            int node = b * BKN + c + lane;
            if (node < N_N) {
                row_ptr[node] = sbase + excl;
                row_len[node] = (unsigned short)x;
            }
            curs[c + lane] = excl;
            carry += __shfl(inc, 63, 64);
        }
    }
    __syncthreads();
    for (int i = threadIdx.x; i < cnt; i += 256) {
        ull rec = recs[i];
        int local = (int)((rec >> 18) & 0x7Fu);
        int pos = sbase + atomicAdd(&curs[local], 1);
        csr_src[pos] = (unsigned)((rec & 0x3FFFFu) << 7);   // byte offset
        csr_val[pos] = __ushort_as_half((unsigned short)(rec >> 36));
    }
}

// ---------- shared inner loop: 2 edges/instruction, LDS record broadcast ----------
// Returns partial sums for 2 columns in accx/accy; caller folds lane halves.
__device__ __forceinline__ void spmm_row(const char* __restrict__ eb,
                                         const unsigned* __restrict__ csr_src,
                                         const __half* __restrict__ csr_val,
                                         int2 (*recs)[64], int wid, int lane,
                                         int hlf, int col4,
                                         int beg, int end,
                                         float& accx, float& accy) {
    for (int base = beg; base < end; base += 64) {
        int2 rec;
        if (base + lane < end) {
            rec.x = (int)csr_src[base + lane];
            rec.y = __float_as_int(__half2float(csr_val[base + lane]));
        } else {
            rec = make_int2(0, 0);   // off=0 safe gather, v=0 contributes nothing
        }
        recs[wid][lane] = rec;       // wave-private LDS, in-order DS pipe
        int cnt = min(64, end - base);
        int j0 = 0;
        for (; j0 + 32 <= cnt; j0 += 32) {          // 32 edges, 16 gathers in flight
            unsigned g[16];
            float v[16];
#pragma unroll
            for (int k = 0; k < 16; ++k) {
                int2 r = recs[wid][j0 + 2 * k + hlf];
                v[k] = __int_as_float(r.y);
                g[k] = *(const unsigned*)(eb + (size_t)(unsigned)r.x + col4);
            }
#pragma unroll
            for (int k = 0; k < 16; ++k) {
                __half2 h = *(__half2*)&g[k];
                accx += __low2float(h) * v[k];
                accy += __high2float(h) * v[k];
            }
        }
        for (; j0 < cnt; j0 += 16) {                // 16-edge tail
            unsigned g[8];
            float v[8];
#pragma unroll
            for (int k = 0; k < 8; ++k) {
                int2 r = recs[wid][j0 + 2 * k + hlf];
                v[k] = __int_as_float(r.y);
                g[k] = *(const unsigned*)(eb + (size_t)(unsigned)r.x + col4);
            }
#pragma unroll
            for (int k = 0; k < 8; ++k) {
                __half2 h = *(__half2*)&g[k];
                accx += __low2float(h) * v[k];
                accy += __high2float(h) * v[k];
            }
        }
    }
}

// ---------- full-table SpMM (layers 1,2) ----------
__global__ __launch_bounds__(256) void spmm16(const __half2* __restrict__ ecur,
                                              __half2* __restrict__ enext,
                                              const int* __restrict__ row_ptr,
                                              const unsigned short* __restrict__ row_len,
                                              const unsigned* __restrict__ csr_src,
                                              const __half* __restrict__ csr_val) {
    __shared__ int2 recs[4][64];
    const int wid = threadIdx.x >> 6;
    const int lane = threadIdx.x & 63;
    const int hlf = lane >> 5;
    const int col = lane & 31;
    int row = blockIdx.x * 4 + wid;
    if (row >= N_N) return;
    int beg = row_ptr[row];
    int end = beg + row_len[row];
    float accx = 0.f, accy = 0.f;
    spmm_row((const char*)ecur, csr_src, csr_val, recs, wid, lane, hlf,
             col * 4, beg, end, accx, accy);
    accx += __shfl_xor(accx, 32, 64);
    accy += __shfl_xor(accy, 32, 64);
    if (lane < 32)
        enext[(size_t)row * 32 + col] = __floats2half2_rn(accx, accy);
}

// ---------- layer-3 SpMM: only the sampled batch rows, accumulate f32 into su/si ----------
__global__ __launch_bounds__(256) void spmm_batch(const __half2* __restrict__ ecur,
                                                  const int* __restrict__ users,
                                                  const int* __restrict__ items,
                                                  const int* __restrict__ row_ptr,
                                                  const unsigned short* __restrict__ row_len,
                                                  const unsigned* __restrict__ csr_src,
                                                  const __half* __restrict__ csr_val,
                                                  float2* __restrict__ su2,
                                                  float2* __restrict__ si2) {
    __shared__ int2 recs[4][64];
    const int wid = threadIdx.x >> 6;
    const int lane = threadIdx.x & 63;
    const int hlf = lane >> 5;
    const int col = lane & 31;
    int r = blockIdx.x * 4 + wid;
    if (r >= 2 * B_N) return;
    int node = (r < B_N) ? users[r] : U_N + items[r - B_N];
    int beg = row_ptr[node];
    int end = beg + row_len[node];
    float accx = 0.f, accy = 0.f;
    spmm_row((const char*)ecur, csr_src, csr_val, recs, wid, lane, hlf,
             col * 4, beg, end, accx, accy);
    accx += __shfl_xor(accx, 32, 64);
    accy += __shfl_xor(accy, 32, 64);
    if (lane < 32) {
        float2* o = (r < B_N) ? (su2 + (size_t)r * 32 + col)
                              : (si2 + (size_t)(r - B_N) * 32 + col);
        float2 t = *o;
        t.x += accx; t.y += accy;
        *o = t;
    }
}

// ---------- layer-0 accumulate from fp32 originals ----------
__global__ __launch_bounds__(256) void accum_f32(const float* __restrict__ ue,
                                                 const float* __restrict__ ie,
                                                 const int* __restrict__ users,
                                                 const int* __restrict__ items,
                                                 float* __restrict__ su,
                                                 float* __restrict__ si) {
    int r = blockIdx.x * 4 + (threadIdx.x >> 6);
    int lane = threadIdx.x & 63;
    if (r >= 2 * B_N) return;
    if (r < B_N) {
        su[(size_t)r * D_DIM + lane] += ue[(size_t)users[r] * D_DIM + lane];
    } else {
        int q = r - B_N;
        si[(size_t)q * D_DIM + lane] += ie[(size_t)items[q] * D_DIM + lane];
    }
}

// ---------- layer accumulate from fp16 table ----------
__global__ __launch_bounds__(256) void accum_h16(const __half* __restrict__ emb,
                                                 const int* __restrict__ users,
                                                 const int* __restrict__ items,
                                                 float* __restrict__ su,
                                                 float* __restrict__ si) {
    int r = blockIdx.x * 4 + (threadIdx.x >> 6);
    int lane = threadIdx.x & 63;
    if (r >= 2 * B_N) return;
    if (r < B_N) {
        su[(size_t)r * D_DIM + lane] +=
            __half2float(emb[(size_t)users[r] * D_DIM + lane]);
    } else {
        int q = r - B_N;
        si[(size_t)q * D_DIM + lane] +=
            __half2float(emb[((size_t)U_N + items[q]) * D_DIM + lane]);
    }
}

// ---------- gamma = su.si/16 + 64*(ub+ib) ----------
__global__ __launch_bounds__(256) void gamma_kernel(const float* __restrict__ su,
                                                    const float* __restrict__ si,
                                                    const float* __restrict__ ub,
                                                    const float* __restrict__ ib,
                                                    const int* __restrict__ users,
                                                    const int* __restrict__ items,
                                                    float* __restrict__ out) {
    int b = blockIdx.x * 4 + (threadIdx.x >> 6);
    int lane = threadIdx.x & 63;
    if (b >= B_N) return;
    float p = su[(size_t)b * D_DIM + lane] * si[(size_t)b * D_DIM + lane];
#pragma unroll
    for (int off = 32; off > 0; off >>= 1) p += __shfl_xor(p, off, 64);
    if (lane == 0) {
        float bias = ub[users[b]] + ib[items[b]];
        out[b] = p * (1.0f / 16.0f) + 64.0f * bias;
    }
}

extern "C" void kernel_launch(void* const* d_in, const int* in_sizes, int n_in,
                              void* d_out, int out_size, void* d_ws, size_t ws_size,
                              hipStream_t stream) {
    const float* user_emb  = (const float*)d_in[0];
    const float* item_emb  = (const float*)d_in[1];
    const float* user_bias = (const float*)d_in[2];
    const float* item_bias = (const float*)d_in[3];
    const float* vals      = (const float*)d_in[4];
    const int*   src       = (const int*)d_in[5];
    const int*   dst       = (const int*)d_in[6];
    const int*   users     = (const int*)d_in[7];
    const int*   items     = (const int*)d_in[8];
    float* out = (float*)d_out;

    char* ws = (char*)d_ws;
    size_t off = 0;
    auto alloc = [&](size_t bytes) -> void* {
        void* p = ws + off;
        off += (bytes + 255) & ~(size_t)255;
        return p;
    };
    const size_t SLOTS = (size_t)NB * CAPB;                                   // 7.2M
    __half* hA      = (__half*)alloc(sizeof(__half) * (size_t)N_N * D_DIM);   // 19.2MB
    __half* hB      = (__half*)alloc(sizeof(__half) * (size_t)N_N * D_DIM);   // 19.2MB
    float*  su      = (float*)alloc(sizeof(float) * (size_t)B_N * D_DIM);     // 4.2MB
    float*  si      = (float*)alloc(sizeof(float) * (size_t)B_N * D_DIM);     // 4.2MB
    int*    row_ptr = (int*)alloc(sizeof(int) * N_N);                         // 0.6MB
    unsigned short* row_len = (unsigned short*)alloc(sizeof(short) * N_N);    // 0.3MB
    int*    bcur    = (int*)alloc(sizeof(int) * NB);
    ull*    staging = (ull*)alloc(sizeof(ull) * SLOTS);                       // 57.6MB
    unsigned* csr_src = (unsigned*)alloc(sizeof(unsigned) * SLOTS);           // 28.8MB
    __half* csr_val = (__half*)alloc(sizeof(__half) * SLOTS);                 // 14.4MB

    hipMemsetAsync(su, 0, sizeof(float) * (size_t)B_N * D_DIM * 2, stream);
    hipMemsetAsync(bcur, 0, sizeof(int) * NB, stream);

    to_half<<<2048, 256, 0, stream>>>((const float2*)user_emb,
                                      (const float2*)item_emb, (__half2*)hA);
    phaseA<<<1024, 1024, 0, stream>>>(src, dst, vals, bcur, staging);
    phaseB<<<NB, 256, 0, stream>>>(staging, bcur, csr_src, csr_val,
                                   row_ptr, row_len);

    // layer 0 contribution from fp32 originals
    accum_f32<<<(2 * B_N) / 4, 256, 0, stream>>>(user_emb, item_emb, users,
                                                 items, su, si);
    // layer 1: hA -> hB (full)
    spmm16<<<(N_N + 3) / 4, 256, 0, stream>>>((const __half2*)hA, (__half2*)hB,
                                              row_ptr, row_len, csr_src, csr_val);
    accum_h16<<<(2 * B_N) / 4, 256, 0, stream>>>(hB, users, items, su, si);
    // layer 2: hB -> hA (full)
    spmm16<<<(N_N + 3) / 4, 256, 0, stream>>>((const __half2*)hB, (__half2*)hA,
                                              row_ptr, row_len, csr_src, csr_val);
    accum_h16<<<(2 * B_N) / 4, 256, 0, stream>>>(hA, users, items, su, si);
    // layer 3: only sampled rows, straight into su/si (fp32)
    spmm_batch<<<(2 * B_N) / 4, 256, 0, stream>>>((const __half2*)hA, users, items,
                                                  row_ptr, row_len, csr_src, csr_val,
                                                  (float2*)su, (float2*)si);

    gamma_kernel<<<B_N / 4, 256, 0, stream>>>(su, si, user_bias, item_bias,
                                              users, items, out);
}